// Round 1
// baseline (1756.217 us; speedup 1.0000x reference)
//
#include <hip/hip_runtime.h>
#include <stdint.h>

// B=4, S=2048, D=1024, H=16, DK=64
// out = [y (4*2048*1024 fp32) | attn (4*16*2048*2048 fp32)]

typedef __attribute__((ext_vector_type(8))) short bf16x8;
typedef __attribute__((ext_vector_type(4))) float f32x4;

__device__ __forceinline__ unsigned short f2bf(float f) {
  union { float f; unsigned int u; } v; v.f = f;
  unsigned int r = v.u + 0x7FFFu + ((v.u >> 16) & 1u);
  return (unsigned short)(r >> 16);
}
__device__ __forceinline__ float bf2f(unsigned short h) {
  union { unsigned int u; float f; } v; v.u = ((unsigned int)h) << 16;
  return v.f;
}

// ---------------------------------------------------------------------------
// GEMM: C[8192][1024](bf16) = A[8192][1024] * W[1024][1024]^T + bias
// A is fp32 (ABF16=false) or bf16 (ABF16=true). W,bias fp32.
// 128x128 tile, BK=32, 4 waves of 64x64, mfma_f32_16x16x32_bf16.
// LDS rows padded to 40 elems (80 B): b128 reads land 2-way/bank = free.
// ---------------------------------------------------------------------------
template <bool ABF16>
__global__ __launch_bounds__(256) void gemm_bias(const void* __restrict__ Av,
                                                 const float* __restrict__ W,
                                                 const float* __restrict__ bias,
                                                 unsigned short* __restrict__ Cout) {
  __shared__ unsigned short As[128 * 40];
  __shared__ unsigned short Ws[128 * 40];
  const int tid = threadIdx.x;
  const int w = tid >> 6, lane = tid & 63, q = lane >> 4, l15 = lane & 15;
  const int wm = w >> 1, wn = w & 1;
  const int m0 = blockIdx.x * 128, n0 = blockIdx.y * 128;

  f32x4 acc[4][4];
#pragma unroll
  for (int i = 0; i < 4; i++)
#pragma unroll
    for (int j = 0; j < 4; j++) acc[i][j] = (f32x4){0.f, 0.f, 0.f, 0.f};

  for (int kt = 0; kt < 32; ++kt) {
    if (ABF16) {
      const unsigned short* A = (const unsigned short*)Av;
#pragma unroll
      for (int j = 0; j < 2; j++) {
        int u = tid + j * 256;          // 512 chunks of 16B (128 rows x 4)
        int r = u >> 2, ch = u & 3;
        uint4 v = *(const uint4*)(A + (size_t)(m0 + r) * 1024 + kt * 32 + ch * 8);
        *(uint4*)(&As[r * 40 + ch * 8]) = v;
      }
    } else {
      const float* A = (const float*)Av;
#pragma unroll
      for (int j = 0; j < 4; j++) {
        int u = tid + j * 256;          // 1024 float4 units (128 rows x 8)
        int r = u >> 3, c4 = u & 7;
        float4 v = *(const float4*)(A + (size_t)(m0 + r) * 1024 + kt * 32 + c4 * 4);
        ushort4 hv = {f2bf(v.x), f2bf(v.y), f2bf(v.z), f2bf(v.w)};
        *(ushort4*)(&As[r * 40 + c4 * 4]) = hv;
      }
    }
#pragma unroll
    for (int j = 0; j < 4; j++) {
      int u = tid + j * 256;
      int r = u >> 3, c4 = u & 7;
      float4 v = *(const float4*)(W + (size_t)(n0 + r) * 1024 + kt * 32 + c4 * 4);
      ushort4 hv = {f2bf(v.x), f2bf(v.y), f2bf(v.z), f2bf(v.w)};
      *(ushort4*)(&Ws[r * 40 + c4 * 4]) = hv;
    }
    __syncthreads();

    bf16x8 af[4], bfr[4];
#pragma unroll
    for (int i = 0; i < 4; i++)
      af[i] = *(const bf16x8*)(&As[(wm * 64 + i * 16 + l15) * 40 + q * 8]);
#pragma unroll
    for (int j = 0; j < 4; j++)
      bfr[j] = *(const bf16x8*)(&Ws[(wn * 64 + j * 16 + l15) * 40 + q * 8]);
#pragma unroll
    for (int i = 0; i < 4; i++)
#pragma unroll
      for (int j = 0; j < 4; j++)
        acc[i][j] = __builtin_amdgcn_mfma_f32_16x16x32_bf16(af[i], bfr[j], acc[i][j], 0, 0, 0);
    __syncthreads();
  }

  // epilogue: C layout col=lane&15, row=quad*4+reg
#pragma unroll
  for (int j = 0; j < 4; j++) {
    int col = n0 + wn * 64 + j * 16 + l15;
    float bv = bias[col];
#pragma unroll
    for (int i = 0; i < 4; i++) {
      int row = m0 + wm * 64 + i * 16 + q * 4;
#pragma unroll
      for (int r2 = 0; r2 < 4; r2++)
        Cout[(size_t)(row + r2) * 1024 + col] = f2bf(acc[i][j][r2] + bv);
    }
  }
}

// ---------------------------------------------------------------------------
// Transpose V per head: Vp[b][s][h*64+d] -> Vt[(b*16+h)][d][s]
// ---------------------------------------------------------------------------
__global__ __launch_bounds__(256) void transpose_v(const unsigned short* __restrict__ Vp,
                                                   unsigned short* __restrict__ Vt) {
  __shared__ unsigned short T[64 * 72];
  int bid = blockIdx.x;  // b*512 + h*32 + st
  int st = bid & 31, h = (bid >> 5) & 15, b = bid >> 9;
  int tid = threadIdx.x;
  int s0 = st * 64;
#pragma unroll
  for (int j = 0; j < 2; j++) {
    int u = tid + j * 256;
    int r = u >> 3, ch = u & 7;
    uint4 v = *(const uint4*)(Vp + ((size_t)b * 2048 + s0 + r) * 1024 + h * 64 + ch * 8);
    *(uint4*)(&T[r * 72 + ch * 8]) = v;
  }
  __syncthreads();
#pragma unroll
  for (int j = 0; j < 2; j++) {
    int u = tid + j * 256;
    int dk = u >> 3, sb = u & 7;
    unsigned short tmp[8];
#pragma unroll
    for (int t = 0; t < 8; t++) tmp[t] = T[(sb * 8 + t) * 72 + dk];
    uint4 o;
    o.x = (unsigned)tmp[0] | ((unsigned)tmp[1] << 16);
    o.y = (unsigned)tmp[2] | ((unsigned)tmp[3] << 16);
    o.z = (unsigned)tmp[4] | ((unsigned)tmp[5] << 16);
    o.w = (unsigned)tmp[6] | ((unsigned)tmp[7] << 16);
    *(uint4*)(Vt + ((size_t)(b * 16 + h) * 64 + dk) * 2048 + s0 + sb * 8) = o;
  }
}

// ---------------------------------------------------------------------------
// Pack mask int32 -> bitmask. mbits[(b*2048+row)*32 + ct] bit c = mask col ct*64+c.
// Each wave: 4096 consecutive ints -> 64 uint64 via __ballot. 2 MiB total out.
// ---------------------------------------------------------------------------
__global__ __launch_bounds__(256) void pack_mask(const int* __restrict__ mask,
                                                 unsigned long long* __restrict__ mbits) {
  int wid = (blockIdx.x * 256 + threadIdx.x) >> 6;  // 4096 waves
  int lane = threadIdx.x & 63;
  size_t base = (size_t)wid * 4096;
  unsigned long long mine = 0;
#pragma unroll 4
  for (int i = 0; i < 64; i++) {
    int v = mask[base + (size_t)i * 64 + lane];
    unsigned long long bits = __ballot(v != 0);
    if (lane == i) mine = bits;
  }
  mbits[(size_t)wid * 64 + lane] = mine;
}

// ---------------------------------------------------------------------------
// Attention: per block = (b, h, 128 Q-rows). Two passes over 32 col-tiles of 64.
// 4 waves; wave w owns rows w*32..w*32+31 (two 16-row groups g).
// Mask via L2-resident bitmask (8B broadcast loads). setprio around MFMA.
// ---------------------------------------------------------------------------
__global__ __launch_bounds__(256) void attn_kernel(const unsigned short* __restrict__ Qp,
                                                   const unsigned short* __restrict__ Kp,
                                                   const unsigned short* __restrict__ Vt,
                                                   const unsigned long long* __restrict__ mbits,
                                                   float* __restrict__ attn,
                                                   unsigned short* __restrict__ O) {
  __shared__ unsigned short Ps[128 * 72];  // Q tile, then reused for P
  __shared__ unsigned short Ks[64 * 72];
  __shared__ unsigned short Vs[64 * 72];
  int bid = blockIdx.x;  // b*256 + h*16 + rb
  int rb = bid & 15, h = (bid >> 4) & 15, b = bid >> 8;
  int row0 = rb * 128;
  int tid = threadIdx.x;
  int w = tid >> 6, lane = tid & 63, q = lane >> 4, l15 = lane & 15;

  // stage Q tile (128 x 64) into Ps
#pragma unroll
  for (int j = 0; j < 4; j++) {
    int u = tid + j * 256;
    int r = u >> 3, ch = u & 7;
    uint4 v = *(const uint4*)(Qp + ((size_t)b * 2048 + row0 + r) * 1024 + h * 64 + ch * 8);
    *(uint4*)(&Ps[r * 72 + ch * 8]) = v;
  }
  __syncthreads();
  bf16x8 aQ[2][2];
#pragma unroll
  for (int g = 0; g < 2; g++)
#pragma unroll
    for (int kc = 0; kc < 2; kc++)
      aQ[g][kc] = *(const bf16x8*)(&Ps[(w * 32 + g * 16 + l15) * 72 + kc * 32 + q * 8]);

  const float SC = 0.125f;     // 1/sqrt(64)
  const float NEGV = -1.0e9f;
  float m[2][4], l[2][4];
#pragma unroll
  for (int g = 0; g < 2; g++)
#pragma unroll
    for (int r2 = 0; r2 < 4; r2++) { m[g][r2] = -1.0e30f; l[g][r2] = 0.f; }
  const size_t mrow_base = (size_t)b * 2048 + row0;

  // ---- pass 1: row max + sum ----
  for (int ct = 0; ct < 32; ++ct) {
#pragma unroll
    for (int j = 0; j < 2; j++) {
      int u = tid + j * 256;
      int r = u >> 3, ch = u & 7;
      uint4 v = *(const uint4*)(Kp + ((size_t)b * 2048 + ct * 64 + r) * 1024 + h * 64 + ch * 8);
      *(uint4*)(&Ks[r * 72 + ch * 8]) = v;
    }
    __syncthreads();
    // mask bits first (L2 latency hides under the MFMAs below)
    unsigned long long mb[2][4];
#pragma unroll
    for (int g = 0; g < 2; g++)
#pragma unroll
      for (int r2 = 0; r2 < 4; r2++) {
        int rowg = w * 32 + g * 16 + q * 4 + r2;
        mb[g][r2] = mbits[(mrow_base + rowg) * 32 + ct] >> l15;
      }
    float s[2][4][4];
    __builtin_amdgcn_s_setprio(1);
#pragma unroll
    for (int nt = 0; nt < 4; nt++) {
      bf16x8 bk0 = *(const bf16x8*)(&Ks[(nt * 16 + l15) * 72 + q * 8]);
      bf16x8 bk1 = *(const bf16x8*)(&Ks[(nt * 16 + l15) * 72 + 32 + q * 8]);
#pragma unroll
      for (int g = 0; g < 2; g++) {
        f32x4 acc = (f32x4){0.f, 0.f, 0.f, 0.f};
        acc = __builtin_amdgcn_mfma_f32_16x16x32_bf16(aQ[g][0], bk0, acc, 0, 0, 0);
        acc = __builtin_amdgcn_mfma_f32_16x16x32_bf16(aQ[g][1], bk1, acc, 0, 0, 0);
#pragma unroll
        for (int r2 = 0; r2 < 4; r2++)
          s[g][nt][r2] = ((mb[g][r2] >> (nt * 16)) & 1ull) ? acc[r2] * SC : NEGV;
      }
    }
    __builtin_amdgcn_s_setprio(0);
#pragma unroll
    for (int g = 0; g < 2; g++)
#pragma unroll
      for (int r2 = 0; r2 < 4; r2++) {
        float rmax = fmaxf(fmaxf(s[g][0][r2], s[g][1][r2]), fmaxf(s[g][2][r2], s[g][3][r2]));
#pragma unroll
        for (int off = 1; off < 16; off <<= 1) rmax = fmaxf(rmax, __shfl_xor(rmax, off));
        float mn = fmaxf(m[g][r2], rmax);
        float rs = __expf(s[g][0][r2] - mn) + __expf(s[g][1][r2] - mn) +
                   __expf(s[g][2][r2] - mn) + __expf(s[g][3][r2] - mn);
#pragma unroll
        for (int off = 1; off < 16; off <<= 1) rs += __shfl_xor(rs, off);
        l[g][r2] = l[g][r2] * __expf(m[g][r2] - mn) + rs;
        m[g][r2] = mn;
      }
    __syncthreads();
  }

  float invl[2][4];
#pragma unroll
  for (int g = 0; g < 2; g++)
#pragma unroll
    for (int r2 = 0; r2 < 4; r2++) invl[g][r2] = 1.0f / l[g][r2];
  f32x4 Oacc[2][4];
#pragma unroll
  for (int g = 0; g < 2; g++)
#pragma unroll
    for (int nd = 0; nd < 4; nd++) Oacc[g][nd] = (f32x4){0.f, 0.f, 0.f, 0.f};

  // ---- pass 2: recompute, write attn, PV ----
  for (int ct = 0; ct < 32; ++ct) {
#pragma unroll
    for (int j = 0; j < 2; j++) {
      int u = tid + j * 256;
      int r = u >> 3, ch = u & 7;
      uint4 v = *(const uint4*)(Kp + ((size_t)b * 2048 + ct * 64 + r) * 1024 + h * 64 + ch * 8);
      *(uint4*)(&Ks[r * 72 + ch * 8]) = v;
      uint4 v2 = *(const uint4*)(Vt + ((size_t)(b * 16 + h) * 64 + r) * 2048 + ct * 64 + ch * 8);
      *(uint4*)(&Vs[r * 72 + ch * 8]) = v2;
    }
    __syncthreads();
    unsigned long long mb[2][4];
#pragma unroll
    for (int g = 0; g < 2; g++)
#pragma unroll
      for (int r2 = 0; r2 < 4; r2++) {
        int rowg = w * 32 + g * 16 + q * 4 + r2;
        mb[g][r2] = mbits[(mrow_base + rowg) * 32 + ct] >> l15;
      }
#pragma unroll
    for (int nt = 0; nt < 4; nt++) {
      bf16x8 bk0 = *(const bf16x8*)(&Ks[(nt * 16 + l15) * 72 + q * 8]);
      bf16x8 bk1 = *(const bf16x8*)(&Ks[(nt * 16 + l15) * 72 + 32 + q * 8]);
#pragma unroll
      for (int g = 0; g < 2; g++) {
        f32x4 acc = (f32x4){0.f, 0.f, 0.f, 0.f};
        acc = __builtin_amdgcn_mfma_f32_16x16x32_bf16(aQ[g][0], bk0, acc, 0, 0, 0);
        acc = __builtin_amdgcn_mfma_f32_16x16x32_bf16(aQ[g][1], bk1, acc, 0, 0, 0);
        int colg = ct * 64 + nt * 16 + l15;
#pragma unroll
        for (int r2 = 0; r2 < 4; r2++) {
          int rowg = row0 + w * 32 + g * 16 + q * 4 + r2;
          float sv = ((mb[g][r2] >> (nt * 16)) & 1ull) ? acc[r2] * SC : NEGV;
          float p = __expf(sv - m[g][r2]) * invl[g][r2];
          attn[((size_t)(b * 16 + h) * 2048 + rowg) * 2048 + colg] = p;
          Ps[(w * 32 + g * 16 + q * 4 + r2) * 72 + nt * 16 + l15] = f2bf(p);
        }
      }
    }
    __syncthreads();
    __builtin_amdgcn_s_setprio(1);
#pragma unroll
    for (int kc = 0; kc < 2; kc++) {
      bf16x8 aP0 = *(const bf16x8*)(&Ps[(w * 32 + l15) * 72 + kc * 32 + q * 8]);
      bf16x8 aP1 = *(const bf16x8*)(&Ps[(w * 32 + 16 + l15) * 72 + kc * 32 + q * 8]);
#pragma unroll
      for (int nd = 0; nd < 4; nd++) {
        bf16x8 bv = *(const bf16x8*)(&Vs[(nd * 16 + l15) * 72 + kc * 32 + q * 8]);
        Oacc[0][nd] = __builtin_amdgcn_mfma_f32_16x16x32_bf16(aP0, bv, Oacc[0][nd], 0, 0, 0);
        Oacc[1][nd] = __builtin_amdgcn_mfma_f32_16x16x32_bf16(aP1, bv, Oacc[1][nd], 0, 0, 0);
      }
    }
    __builtin_amdgcn_s_setprio(0);
    __syncthreads();
  }

#pragma unroll
  for (int g = 0; g < 2; g++)
#pragma unroll
    for (int nd = 0; nd < 4; nd++)
#pragma unroll
      for (int r2 = 0; r2 < 4; r2++) {
        int rowg = row0 + w * 32 + g * 16 + q * 4 + r2;
        O[((size_t)b * 2048 + rowg) * 1024 + h * 64 + nd * 16 + l15] = f2bf(Oacc[g][nd][r2]);
      }
}

// ---------------------------------------------------------------------------
// LayerNorm epilogue: x = P(bf16, has bias already) + residual; y = LN(x)*g+b
// One block per row of 1024.
// ---------------------------------------------------------------------------
__global__ __launch_bounds__(256) void ln_kernel(const unsigned short* __restrict__ P,
                                                 const float* __restrict__ resid,
                                                 const float* __restrict__ gamma,
                                                 const float* __restrict__ beta,
                                                 float* __restrict__ y) {
  __shared__ float red[16];
  int row = blockIdx.x;
  int tid = threadIdx.x;
  size_t base = (size_t)row * 1024;
  int c = tid * 4;
  ushort4 pv = *(const ushort4*)(P + base + c);
  float4 rv = *(const float4*)(resid + base + c);
  float x0 = bf2f(pv.x) + rv.x;
  float x1 = bf2f(pv.y) + rv.y;
  float x2 = bf2f(pv.z) + rv.z;
  float x3 = bf2f(pv.w) + rv.w;
  float s1 = x0 + x1 + x2 + x3;
  float s2 = x0 * x0 + x1 * x1 + x2 * x2 + x3 * x3;
#pragma unroll
  for (int off = 32; off >= 1; off >>= 1) {
    s1 += __shfl_xor(s1, off);
    s2 += __shfl_xor(s2, off);
  }
  int w = tid >> 6;
  if ((tid & 63) == 0) { red[w] = s1; red[w + 8] = s2; }
  __syncthreads();
  float ts1 = red[0] + red[1] + red[2] + red[3];
  float ts2 = red[8] + red[9] + red[10] + red[11];
  float mu = ts1 * (1.0f / 1024.0f);
  float var = ts2 * (1.0f / 1024.0f) - mu * mu;
  float rstd = rsqrtf(var + 1e-5f);
  float4 gv = *(const float4*)(gamma + c);
  float4 be = *(const float4*)(beta + c);
  float4 o;
  o.x = (x0 - mu) * rstd * gv.x + be.x;
  o.y = (x1 - mu) * rstd * gv.y + be.y;
  o.z = (x2 - mu) * rstd * gv.z + be.z;
  o.w = (x3 - mu) * rstd * gv.w + be.w;
  *(float4*)(y + base + c) = o;
}

// ---------------------------------------------------------------------------
extern "C" void kernel_launch(void* const* d_in, const int* in_sizes, int n_in,
                              void* d_out, int out_size, void* d_ws, size_t ws_size,
                              hipStream_t stream) {
  (void)in_sizes; (void)n_in; (void)out_size; (void)ws_size;
  const float* query = (const float*)d_in[0];
  const float* key   = (const float*)d_in[1];
  const float* value = (const float*)d_in[2];
  const int*   mask  = (const int*)d_in[3];
  const float* Wq = (const float*)d_in[4];
  const float* bq = (const float*)d_in[5];
  const float* Wk = (const float*)d_in[6];
  const float* bk = (const float*)d_in[7];
  const float* Wv = (const float*)d_in[8];
  const float* bv = (const float*)d_in[9];
  const float* Wo = (const float*)d_in[10];
  const float* bo = (const float*)d_in[11];
  const float* gamma = (const float*)d_in[12];
  const float* beta  = (const float*)d_in[13];

  char* ws = (char*)d_ws;
  const size_t SEG = 16777216;  // 8192*1024*2 bytes
  unsigned short* Qp   = (unsigned short*)(ws + 0 * SEG);
  unsigned short* Kp   = (unsigned short*)(ws + 1 * SEG);
  unsigned short* Vp   = (unsigned short*)(ws + 2 * SEG);
  unsigned short* Vt   = (unsigned short*)(ws + 3 * SEG);
  unsigned short* O    = (unsigned short*)(ws + 4 * SEG);
  unsigned short* Pout = (unsigned short*)(ws + 5 * SEG);
  // mask bitpack aliases the Vp segment (dead after transpose_v): 2 MiB
  unsigned long long* mbits = (unsigned long long*)(ws + 2 * SEG);

  float* y = (float*)d_out;
  float* attn = (float*)d_out + 8388608;  // 4*2048*1024

  dim3 blk(256);
  dim3 ggrid(64, 8);
  gemm_bias<false><<<ggrid, blk, 0, stream>>>((const void*)query, Wq, bq, Qp);
  gemm_bias<false><<<ggrid, blk, 0, stream>>>((const void*)key,   Wk, bk, Kp);
  gemm_bias<false><<<ggrid, blk, 0, stream>>>((const void*)value, Wv, bv, Vp);
  transpose_v<<<dim3(2048), blk, 0, stream>>>(Vp, Vt);
  pack_mask<<<dim3(1024), blk, 0, stream>>>(mask, mbits);   // after transpose_v (aliases Vp)
  attn_kernel<<<dim3(1024), blk, 0, stream>>>(Qp, Kp, Vt, mbits, attn, O);
  gemm_bias<true><<<ggrid, blk, 0, stream>>>((const void*)O, Wo, bo, Pout);
  ln_kernel<<<dim3(8192), blk, 0, stream>>>(Pout, query, gamma, beta, y);
}